// Round 3
// baseline (633.673 us; speedup 1.0000x reference)
//
#include <hip/hip_runtime.h>
#include <math.h>

// Problem constants (WaveletAtt: B=2, CIN=DIM=256, HEADS=8, wt_levels=1 Haar)
constexpr int B_ = 2;
constexpr int C_ = 256;
constexpr int Hb_ = 128, Wb_ = 128;      // crossFeat / k / v / output spatial
constexpr int Nb_ = Hb_ * Wb_;           // 16384
constexpr int Hs_ = 64, Ws_ = 64;        // x / q spatial
constexpr int Ns_ = Hs_ * Ws_;           // 4096
constexpr int HEADS_ = 8;
constexpr int CHD_ = C_ / HEADS_;        // 32

// compile-time log2
template<int N> struct Log2 { static constexpr int v = 1 + Log2<N / 2>::v; };
template<> struct Log2<1> { static constexpr int v = 0; };

// ---------------------------------------------------------------------------
// GEMM: out[b][o][n] = sum_c W[o][c] * in[b][c][n]   (1x1 conv, f32 VALU)
// 64x64 block tile, 256 threads, 4x4 per-thread micro-tile, K-step 16.
// ---------------------------------------------------------------------------
template<int NTOT>
__global__ __launch_bounds__(256) void gemm_1x1(const float* __restrict__ in,
                                                const float* __restrict__ Wm,
                                                float* __restrict__ out) {
  __shared__ float Wsh[16][65];   // [kk][oo], +1 pad
  __shared__ float Xsh[16][64];   // [kk][nn]
  const int b  = blockIdx.z;
  const int o0 = blockIdx.y * 64;
  const int n0 = blockIdx.x * 64;
  const float* inb = in + (size_t)b * C_ * NTOT;
  const int t  = threadIdx.x;
  const int ty = t >> 4, tx = t & 15;
  float acc[4][4] = {};
  for (int k = 0; k < C_; k += 16) {
    { // stage W tile (64 o x 16 c), one float4 per thread
      int oo  = t >> 2;
      int kk4 = (t & 3) << 2;
      float4 wv = *(const float4*)(Wm + (size_t)(o0 + oo) * C_ + k + kk4);
      Wsh[kk4 + 0][oo] = wv.x; Wsh[kk4 + 1][oo] = wv.y;
      Wsh[kk4 + 2][oo] = wv.z; Wsh[kk4 + 3][oo] = wv.w;
    }
    { // stage X tile (16 c x 64 n), one float4 per thread
      int kr = t >> 4;
      int nn = (t & 15) << 2;
      *(float4*)&Xsh[kr][nn] = *(const float4*)(inb + (size_t)(k + kr) * NTOT + n0 + nn);
    }
    __syncthreads();
#pragma unroll
    for (int kk = 0; kk < 16; ++kk) {
      float av[4], xv[4];
#pragma unroll
      for (int i = 0; i < 4; ++i) av[i] = Wsh[kk][ty * 4 + i];
#pragma unroll
      for (int j = 0; j < 4; ++j) xv[j] = Xsh[kk][tx * 4 + j];
#pragma unroll
      for (int i = 0; i < 4; ++i)
#pragma unroll
        for (int j = 0; j < 4; ++j)
          acc[i][j] = fmaf(av[i], xv[j], acc[i][j]);
    }
    __syncthreads();
  }
  float* ob = out + (size_t)b * C_ * NTOT;
#pragma unroll
  for (int i = 0; i < 4; ++i)
    *(float4*)(ob + (size_t)(o0 + ty * 4 + i) * NTOT + n0 + tx * 4) =
        make_float4(acc[i][0], acc[i][1], acc[i][2], acc[i][3]);
}

// ---------------------------------------------------------------------------
// Haar analysis: s[b][c*4+f][i][j] from 2x2 blocks of x[b][c][...]
// DEC: LL, HL(hi-rows), LH(hi-cols), HH — each +/-0.5 butterflies.
// Compile-time dims => shift/mask indexing.
// ---------------------------------------------------------------------------
template<int HC, int WC>
__global__ void wt_analysis(const float* __restrict__ x, float* __restrict__ s) {
  constexpr int H2 = HC / 2, W2 = WC / 2;
  constexpr int LW2 = Log2<W2>::v, LH2 = Log2<H2>::v;
  const int total = B_ * C_ * H2 * W2;
  int idx = blockIdx.x * blockDim.x + threadIdx.x;
  if (idx >= total) return;
  int j = idx & (W2 - 1); int tmp = idx >> LW2;
  int i = tmp & (H2 - 1); tmp >>= LH2;
  int c = tmp & (C_ - 1); int b = tmp >> 8;
  const float* xp = x + (((size_t)(b * C_ + c) * HC + 2 * i) * WC) + 2 * j;
  float p00 = xp[0], p01 = xp[1];
  float p10 = xp[WC], p11 = xp[WC + 1];
  float ll = 0.5f * (p00 + p01 + p10 + p11);
  float hl = 0.5f * (p00 + p01 - p10 - p11);   // f=1: hi rows x lo cols
  float lh = 0.5f * (p00 - p01 + p10 - p11);   // f=2: lo rows x hi cols
  float hh = 0.5f * (p00 - p01 - p10 + p11);   // f=3
  constexpr size_t fs = (size_t)H2 * W2;
  size_t so = (((size_t)b * (4 * C_) + c * 4) * H2 + i) * W2 + j;
  s[so] = ll; s[so + fs] = hl; s[so + 2 * fs] = lh; s[so + 3 * fs] = hh;
}

// ---------------------------------------------------------------------------
// Depthwise 3x3, SAME zero-pad, * per-channel scale (wavelet-domain conv)
// ---------------------------------------------------------------------------
template<int CH, int HC, int WC>
__global__ void dw3x3_scale(const float* __restrict__ in, const float* __restrict__ w9,
                            const float* __restrict__ scale, float* __restrict__ out) {
  constexpr int LW = Log2<WC>::v, LH = Log2<HC>::v;
  const int total = B_ * CH * HC * WC;
  int idx = blockIdx.x * blockDim.x + threadIdx.x;
  if (idx >= total) return;
  int j = idx & (WC - 1); int tmp = idx >> LW;
  int i = tmp & (HC - 1); tmp >>= LH;
  int c = tmp & (CH - 1);
  const float* ip = in + ((size_t)(idx >> (LW + LH)) << (LW + LH));  // [b][c] plane base
  const float* wp = w9 + c * 9;
  float acc = 0.f;
#pragma unroll
  for (int dh = -1; dh <= 1; ++dh) {
    int ii = i + dh;
    if ((unsigned)ii < (unsigned)HC) {
#pragma unroll
      for (int dw = -1; dw <= 1; ++dw) {
        int jj = j + dw;
        if ((unsigned)jj < (unsigned)WC)
          acc = fmaf(ip[(ii << LW) + jj], wp[(dh + 1) * 3 + (dw + 1)], acc);
      }
    }
  }
  out[idx] = acc * scale[c];
}

// ---------------------------------------------------------------------------
// Base depthwise 3x3 * base_s + Haar synthesis of conv'd subbands
// ---------------------------------------------------------------------------
template<int HC, int WC>
__global__ void wt_recon_base(const float* __restrict__ x, const float* __restrict__ sp,
                              const float* __restrict__ bw, const float* __restrict__ bs,
                              float* __restrict__ out) {
  constexpr int LW = Log2<WC>::v, LH = Log2<HC>::v;
  constexpr int H2 = HC / 2, W2 = WC / 2;
  const int total = B_ * C_ * HC * WC;
  int idx = blockIdx.x * blockDim.x + threadIdx.x;
  if (idx >= total) return;
  int w = idx & (WC - 1); int tmp = idx >> LW;
  int h = tmp & (HC - 1); tmp >>= LH;
  int c = tmp & (C_ - 1); int b = tmp >> 8;
  const float* ip = x + (((size_t)idx >> (LW + LH)) << (LW + LH));
  const float* wp = bw + c * 9;
  float acc = 0.f;
#pragma unroll
  for (int dh = -1; dh <= 1; ++dh) {
    int ii = h + dh;
    if ((unsigned)ii < (unsigned)HC) {
#pragma unroll
      for (int dw = -1; dw <= 1; ++dw) {
        int jj = w + dw;
        if ((unsigned)jj < (unsigned)WC)
          acc = fmaf(ip[(ii << LW) + jj], wp[(dh + 1) * 3 + (dw + 1)], acc);
      }
    }
  }
  acc *= bs[c];
  constexpr size_t fs = (size_t)H2 * W2;
  size_t so = (((size_t)b * (4 * C_) + c * 4) * H2 + (h >> 1)) * W2 + (w >> 1);
  float s0 = sp[so], s1 = sp[so + fs], s2 = sp[so + 2 * fs], s3 = sp[so + 3 * fs];
  float sgp = (h & 1) ? -1.f : 1.f;   // REC row sign
  float sgq = (w & 1) ? -1.f : 1.f;   // REC col sign
  acc += 0.5f * (s0 + sgp * s1 + sgq * s2 + sgp * sgq * s3);
  out[idx] = acc;
}

// ---------------------------------------------------------------------------
// Bilinear 2x upsample 64->128, align_corners=False (== jax.image.resize;
// edge weight-renormalization == index clamping for scale-2, verified)
// ---------------------------------------------------------------------------
__global__ void resize2x(const float* __restrict__ in, float* __restrict__ out) {
  const int total = B_ * C_ * Hb_ * Wb_;
  int idx = blockIdx.x * blockDim.x + threadIdx.x;
  if (idx >= total) return;
  int j = idx & (Wb_ - 1); int tmp = idx >> 7;
  int i = tmp & (Hb_ - 1); tmp >>= 7;
  int bc = tmp;
  int ti = i >> 1; bool oi = i & 1;
  int r0 = oi ? ti : ti - 1;  int r1 = oi ? ti + 1 : ti;
  float wr0 = oi ? 0.75f : 0.25f, wr1 = oi ? 0.25f : 0.75f;
  r0 = r0 < 0 ? 0 : r0;  r1 = r1 > Hs_ - 1 ? Hs_ - 1 : r1;
  int tj = j >> 1; bool oj = j & 1;
  int c0 = oj ? tj : tj - 1;  int c1 = oj ? tj + 1 : tj;
  float wc0 = oj ? 0.75f : 0.25f, wc1 = oj ? 0.25f : 0.75f;
  c0 = c0 < 0 ? 0 : c0;  c1 = c1 > Ws_ - 1 ? Ws_ - 1 : c1;
  const float* ip = in + (size_t)bc * Ns_;
  float v = wr0 * (wc0 * ip[r0 * Ws_ + c0] + wc1 * ip[r0 * Ws_ + c1]) +
            wr1 * (wc0 * ip[r1 * Ws_ + c0] + wc1 * ip[r1 * Ws_ + c1]);
  out[idx] = v;
}

// ---------------------------------------------------------------------------
// Reciprocal L2 norms for q_up and k1 in one launch.
// blocks [0,512): q rows; [512,1024): k rows. 256 threads each.
// ---------------------------------------------------------------------------
__global__ void rownorm2(const float* __restrict__ q, const float* __restrict__ k,
                         float* __restrict__ rnq, float* __restrict__ rnk) {
  const int blk = blockIdx.x;
  const bool isK = blk >= B_ * C_;
  const int bc = isK ? blk - B_ * C_ : blk;
  const float* p = (isK ? k : q) + (size_t)bc * Nb_;
  float acc = 0.f;
  for (int n = threadIdx.x; n < Nb_; n += blockDim.x) {
    float v = p[n];
    acc = fmaf(v, v, acc);
  }
#pragma unroll
  for (int m = 32; m; m >>= 1) acc += __shfl_xor(acc, m, 64);
  __shared__ float red[4];
  int lane = threadIdx.x & 63, wv = threadIdx.x >> 6;
  if (lane == 0) red[wv] = acc;
  __syncthreads();
  if (threadIdx.x == 0) {
    float s = red[0] + red[1] + red[2] + red[3];
    (isK ? rnk : rnq)[bc] = 1.f / fmaxf(sqrtf(s), 1e-12f);
  }
}

__global__ void zero_buf(float* __restrict__ p, int n) {
  int i = blockIdx.x * blockDim.x + threadIdx.x;
  if (i < n) p[i] = 0.f;
}

// ---------------------------------------------------------------------------
// Gram: gram[b][h][c][d] += sum_{n in slice} q[b][h*32+c][n] * k[b][h*32+d][n]
// grid (32 slices, 8 heads, 2 b), block 1024 (one thread per (c,d))
// ---------------------------------------------------------------------------
__global__ __launch_bounds__(1024) void gram_qk(const float* __restrict__ q,
                                                const float* __restrict__ k,
                                                float* __restrict__ gram) {
  const int b = blockIdx.z, h = blockIdx.y, sl = blockIdx.x;
  constexpr int NS = Nb_ / 32;   // 512 n per slice
  const int n0 = sl * NS;
  const int t = threadIdx.x;
  const int c = t >> 5, d = t & 31;
  const float* qb = q + ((size_t)b * C_ + h * CHD_) * Nb_;
  const float* kb = k + ((size_t)b * C_ + h * CHD_) * Nb_;
  __shared__ float qs[32][66], ks[32][66];
  float acc = 0.f;
  for (int nc = 0; nc < NS; nc += 64) {
    int lr = t >> 5;
    int lc = (t & 31) * 2;
    *(float2*)&qs[lr][lc] = *(const float2*)&qb[(size_t)lr * Nb_ + n0 + nc + lc];
    *(float2*)&ks[lr][lc] = *(const float2*)&kb[(size_t)lr * Nb_ + n0 + nc + lc];
    __syncthreads();
#pragma unroll
    for (int nn = 0; nn < 64; ++nn) acc = fmaf(qs[c][nn], ks[d][nn], acc);
    __syncthreads();
  }
  atomicAdd(&gram[((size_t)(b * HEADS_ + h) * CHD_ + c) * CHD_ + d], acc);
}

// ---------------------------------------------------------------------------
// attn = softmax_d( gram * rnq_c * rnk_d * temp_h )   — 32x32 per (b,h)
// ---------------------------------------------------------------------------
__global__ __launch_bounds__(1024) void attn_softmax(const float* __restrict__ gram,
                                                     const float* __restrict__ rnq,
                                                     const float* __restrict__ rnk,
                                                     const float* __restrict__ temp,
                                                     float* __restrict__ attn) {
  const int h = blockIdx.x, b = blockIdx.y;
  const int t = threadIdx.x;
  const int c = t >> 5, d = t & 31;
  size_t gi = ((size_t)(b * HEADS_ + h) * CHD_ + c) * CHD_ + d;
  float val = gram[gi] * rnq[b * C_ + h * CHD_ + c] * rnk[b * C_ + h * CHD_ + d] * temp[h];
  float m = val;
#pragma unroll
  for (int s = 16; s; s >>= 1) m = fmaxf(m, __shfl_xor(m, s, 64));
  float e = expf(val - m);
  float ssum = e;
#pragma unroll
  for (int s = 16; s; s >>= 1) ssum += __shfl_xor(ssum, s, 64);
  attn[gi] = e / ssum;
}

// ---------------------------------------------------------------------------
// out[b][h*32+c][n] = sum_d attn[b][h][c][d] * v[b][h*32+d][n]
// grid (Nb/256, 16), block 256: each thread one n, v column in registers
// ---------------------------------------------------------------------------
__global__ __launch_bounds__(256) void av_apply(const float* __restrict__ attn,
                                                const float* __restrict__ v,
                                                float* __restrict__ out) {
  const int bh = blockIdx.y;
  const int b = bh >> 3, h = bh & 7;
  const int n = blockIdx.x * 256 + threadIdx.x;
  __shared__ float a[32][33];
  for (int i = threadIdx.x; i < 1024; i += 256) a[i >> 5][i & 31] = attn[(size_t)bh * 1024 + i];
  __syncthreads();
  const float* vb = v + ((size_t)b * C_ + h * CHD_) * Nb_ + n;
  float vr[32];
#pragma unroll
  for (int d = 0; d < 32; ++d) vr[d] = vb[(size_t)d * Nb_];
  float* ob = out + ((size_t)b * C_ + h * CHD_) * Nb_ + n;
#pragma unroll
  for (int c = 0; c < 32; ++c) {
    float acc = 0.f;
#pragma unroll
    for (int d = 0; d < 32; ++d) acc = fmaf(a[c][d], vr[d], acc);
    ob[(size_t)c * Nb_] = acc;
  }
}

// ---------------------------------------------------------------------------
// proj wtconv: 1x1 depthwise kernels => closed form per 2x2 block, one kernel
// ---------------------------------------------------------------------------
__global__ void proj_wtconv1x1(const float* __restrict__ x, const float* __restrict__ bw,
                               const float* __restrict__ bs, const float* __restrict__ ww,
                               const float* __restrict__ wsc, float* __restrict__ out) {
  const int total = B_ * C_ * (Hb_ / 2) * (Wb_ / 2);
  int idx = blockIdx.x * blockDim.x + threadIdx.x;
  if (idx >= total) return;
  int j = idx & 63; int tmp = idx >> 6;
  int i = tmp & 63; tmp >>= 6;
  int c = tmp & (C_ - 1); int b = tmp >> 8;
  const float* ip = x + ((size_t)(b * C_ + c) * Hb_ + 2 * i) * Wb_ + 2 * j;
  float p00 = ip[0], p01 = ip[1], p10 = ip[Wb_], p11 = ip[Wb_ + 1];
  float ll = 0.5f * (p00 + p01 + p10 + p11);
  float hl = 0.5f * (p00 + p01 - p10 - p11);
  float lh = 0.5f * (p00 - p01 + p10 - p11);
  float hh = 0.5f * (p00 - p01 - p10 + p11);
  ll *= ww[c * 4 + 0] * wsc[c * 4 + 0];
  hl *= ww[c * 4 + 1] * wsc[c * 4 + 1];
  lh *= ww[c * 4 + 2] * wsc[c * 4 + 2];
  hh *= ww[c * 4 + 3] * wsc[c * 4 + 3];
  float bb = bw[c] * bs[c];
  float* op = out + ((size_t)(b * C_ + c) * Hb_ + 2 * i) * Wb_ + 2 * j;
  op[0]        = p00 * bb + 0.5f * (ll + hl + lh + hh);
  op[1]        = p01 * bb + 0.5f * (ll + hl - lh - hh);
  op[Wb_]      = p10 * bb + 0.5f * (ll - hl + lh - hh);
  op[Wb_ + 1]  = p11 * bb + 0.5f * (ll - hl - lh + hh);
}

// ---------------------------------------------------------------------------
extern "C" void kernel_launch(void* const* d_in, const int* in_sizes, int n_in,
                              void* d_out, int out_size, void* d_ws, size_t ws_size,
                              hipStream_t stream) {
  const float* x    = (const float*)d_in[0];
  const float* cf   = (const float*)d_in[1];
  const float* Wq   = (const float*)d_in[2];
  const float* Wk   = (const float*)d_in[3];
  const float* Wv   = (const float*)d_in[4];
  const float* temp = (const float*)d_in[5];
  const float* q_bw = (const float*)d_in[6];
  const float* q_bs = (const float*)d_in[7];
  const float* q_ww = (const float*)d_in[8];
  const float* q_ws = (const float*)d_in[9];
  const float* k_bw = (const float*)d_in[10];
  const float* k_bs = (const float*)d_in[11];
  const float* k_ww = (const float*)d_in[12];
  const float* k_ws = (const float*)d_in[13];
  const float* v_bw = (const float*)d_in[14];
  const float* v_bs = (const float*)d_in[15];
  const float* v_ww = (const float*)d_in[16];
  const float* v_ws = (const float*)d_in[17];
  const float* p_bw = (const float*)d_in[18];
  const float* p_bs = (const float*)d_in[19];
  const float* p_ww = (const float*)d_in[20];
  const float* p_ws = (const float*)d_in[21];

  // Workspace layout (floats). Liveness-based reuse:
  //   Bb: k0, then (k0 dead after k-wtconv) q_up.  Cb: v0, then out_att.
  float* ws   = (float*)d_ws;
  float* A    = ws;                 // q0   [2,256,64,64]    2,097,152
  float* Bb   = A  + 2097152;       // k0 -> q_up            8,388,608
  float* Cb   = Bb + 8388608;       // v0 -> out_att         8,388,608
  float* Db   = Cb + 8388608;       // s scratch             8,388,608
  float* Eb   = Db + 8388608;       // s' scratch            8,388,608
  float* Fb   = Eb + 8388608;       // q1   [2,256,64,64]    2,097,152
  float* Gb   = Fb + 2097152;       // k1                    8,388,608
  float* Hb   = Gb + 8388608;       // v1                    8,388,608
  float* rnq  = Hb + 8388608;       // 512
  float* rnk  = rnq + 512;          // 512
  float* gram = rnk + 512;          // 16384
  float* attn = gram + 16384;       // 16384

  const int TPB = 256;
  auto nblk = [](int total, int tpb) { return (total + tpb - 1) / tpb; };

  // 1) q/k/v 1x1 channel-mix GEMMs
  gemm_1x1<Ns_><<<dim3(Ns_ / 64, C_ / 64, B_), 256, 0, stream>>>(x,  Wq, A);
  gemm_1x1<Nb_><<<dim3(Nb_ / 64, C_ / 64, B_), 256, 0, stream>>>(cf, Wk, Bb);
  gemm_1x1<Nb_><<<dim3(Nb_ / 64, C_ / 64, B_), 256, 0, stream>>>(cf, Wv, Cb);

  // 2) wtconv(q)  (64x64)
  wt_analysis<Hs_, Ws_><<<nblk(B_ * C_ * 32 * 32, TPB), TPB, 0, stream>>>(A, Db);
  dw3x3_scale<1024, 32, 32><<<nblk(B_ * 1024 * 32 * 32, TPB), TPB, 0, stream>>>(Db, q_ww, q_ws, Eb);
  wt_recon_base<Hs_, Ws_><<<nblk(B_ * C_ * Ns_, TPB), TPB, 0, stream>>>(A, Eb, q_bw, q_bs, Fb);

  // 3) wtconv(k)  (128x128)
  wt_analysis<Hb_, Wb_><<<nblk(B_ * C_ * 64 * 64, TPB), TPB, 0, stream>>>(Bb, Db);
  dw3x3_scale<1024, 64, 64><<<nblk(B_ * 1024 * 64 * 64, TPB), TPB, 0, stream>>>(Db, k_ww, k_ws, Eb);
  wt_recon_base<Hb_, Wb_><<<nblk(B_ * C_ * Nb_, TPB), TPB, 0, stream>>>(Bb, Eb, k_bw, k_bs, Gb);

  // 4) wtconv(v)  (128x128)
  wt_analysis<Hb_, Wb_><<<nblk(B_ * C_ * 64 * 64, TPB), TPB, 0, stream>>>(Cb, Db);
  dw3x3_scale<1024, 64, 64><<<nblk(B_ * 1024 * 64 * 64, TPB), TPB, 0, stream>>>(Db, v_ww, v_ws, Eb);
  wt_recon_base<Hb_, Wb_><<<nblk(B_ * C_ * Nb_, TPB), TPB, 0, stream>>>(Cb, Eb, v_bw, v_bs, Hb);

  // 5) bilinear 2x upsample q1 -> q_up (reuses k0's buffer Bb; k0 is dead)
  resize2x<<<nblk(B_ * C_ * Nb_, TPB), TPB, 0, stream>>>(Fb, Bb);

  // 6) reciprocal L2 norms along spatial dim (q_up and k1, one launch)
  rownorm2<<<2 * B_ * C_, 256, 0, stream>>>(Bb, Gb, rnq, rnk);

  // 7) gram + softmax -> attn [2,8,32,32]
  zero_buf<<<nblk(B_ * HEADS_ * CHD_ * CHD_, TPB), TPB, 0, stream>>>(gram, B_ * HEADS_ * CHD_ * CHD_);
  gram_qk<<<dim3(32, HEADS_, B_), 1024, 0, stream>>>(Bb, Gb, gram);
  attn_softmax<<<dim3(HEADS_, B_), 1024, 0, stream>>>(gram, rnq, rnk, temp, attn);

  // 8) out_att = attn @ v   (writes into Cb; v0 dead)
  av_apply<<<dim3(Nb_ / 256, B_ * HEADS_), 256, 0, stream>>>(attn, Hb, Cb);

  // 9) proj wtconv (1x1 kernels => fused closed form) -> d_out
  proj_wtconv1x1<<<nblk(B_ * C_ * 64 * 64, TPB), TPB, 0, stream>>>(
      Cb, p_bw, p_bs, p_ww, p_ws, (float*)d_out);
}

// Round 4
// 485.604 us; speedup vs baseline: 1.3049x; 1.3049x over previous
//
#include <hip/hip_runtime.h>
#include <math.h>

// WaveletAtt: B=2, CIN=DIM=256, HEADS=8, wt_levels=1 Haar
constexpr int B_ = 2;
constexpr int C_ = 256;
constexpr int Hb_ = 128, Wb_ = 128;      // crossFeat / k / v / output spatial
constexpr int Nb_ = Hb_ * Wb_;           // 16384
constexpr int Hs_ = 64, Ws_ = 64;        // x / q spatial
constexpr int Ns_ = Hs_ * Ws_;           // 4096
constexpr int HEADS_ = 8;
constexpr int CHD_ = C_ / HEADS_;        // 32

// ---------------------------------------------------------------------------
// GEMM v2: out[b][o][n] = sum_c W[o][c] * in[b][c][n]
// 64(M)x128(N) tile, 256 threads, 4x8 micro-tile, BK=32 (8 k-steps, 16 barriers)
// ---------------------------------------------------------------------------
template<int NTOT>
__global__ __launch_bounds__(256) void gemm_1x1(const float* __restrict__ in,
                                                const float* __restrict__ Wm,
                                                float* __restrict__ out) {
  constexpr int BK = 32;
  __shared__ float Wsh[BK][65];    // [k][o], +1 pad
  __shared__ float Xsh[BK][128];   // [k][n]
  const int b  = blockIdx.z;
  const int o0 = blockIdx.y * 64;
  const int n0 = blockIdx.x * 128;
  const float* inb = in + (size_t)b * C_ * NTOT;
  const int t  = threadIdx.x;
  const int ty = t >> 4, tx = t & 15;   // ty: 4 M-rows each; tx: 8 N-cols each
  float acc[4][8] = {};
  for (int k0 = 0; k0 < C_; k0 += BK) {
    { // stage W tile (64 o x 32 k): 8 k per thread from one o-row
      int oo = t >> 2, kb = (t & 3) << 3;
      const float* wp = Wm + (size_t)(o0 + oo) * C_ + k0 + kb;
      float4 w0 = *(const float4*)wp;
      float4 w1 = *(const float4*)(wp + 4);
      Wsh[kb + 0][oo] = w0.x; Wsh[kb + 1][oo] = w0.y;
      Wsh[kb + 2][oo] = w0.z; Wsh[kb + 3][oo] = w0.w;
      Wsh[kb + 4][oo] = w1.x; Wsh[kb + 5][oo] = w1.y;
      Wsh[kb + 6][oo] = w1.z; Wsh[kb + 7][oo] = w1.w;
    }
    { // stage X tile (32 k x 128 n): lanes cover a row contiguously
      int nn = (t & 31) << 2;
      int kr0 = t >> 5;               // 0..7
#pragma unroll
      for (int r = 0; r < 4; ++r) {
        int kr = kr0 + r * 8;
        *(float4*)&Xsh[kr][nn] = *(const float4*)(inb + (size_t)(k0 + kr) * NTOT + n0 + nn);
      }
    }
    __syncthreads();
#pragma unroll
    for (int kk = 0; kk < BK; ++kk) {
      float av[4];
#pragma unroll
      for (int i = 0; i < 4; ++i) av[i] = Wsh[kk][ty * 4 + i];
      float4 x0 = *(float4*)&Xsh[kk][tx * 8];
      float4 x1 = *(float4*)&Xsh[kk][tx * 8 + 4];
      float xv[8] = {x0.x, x0.y, x0.z, x0.w, x1.x, x1.y, x1.z, x1.w};
#pragma unroll
      for (int i = 0; i < 4; ++i)
#pragma unroll
        for (int j = 0; j < 8; ++j)
          acc[i][j] = fmaf(av[i], xv[j], acc[i][j]);
    }
    __syncthreads();
  }
  float* ob = out + (size_t)b * C_ * NTOT;
#pragma unroll
  for (int i = 0; i < 4; ++i) {
    float* op = ob + (size_t)(o0 + ty * 4 + i) * NTOT + n0 + tx * 8;
    *(float4*)op       = make_float4(acc[i][0], acc[i][1], acc[i][2], acc[i][3]);
    *(float4*)(op + 4) = make_float4(acc[i][4], acc[i][5], acc[i][6], acc[i][7]);
  }
}

// ---------------------------------------------------------------------------
// Fused WTConv (wt_levels=1 Haar, 3x3 wavelet + 3x3 base), one 64x64 output
// tile per block. Haar analysis -> dw3x3(subbands)*scale -> synthesis + base
// dw3x3*base_s, all in LDS. Zero-filled input halo reproduces both the
// subband zero-pad (analysis of 0 = 0) and the base-conv zero-pad exactly.
// Optional: accumulate sum(out^2) per (b,c) row into nrm (for L2 norm fold).
// ---------------------------------------------------------------------------
template<int HP>   // plane is HP x HP (64 or 128)
__global__ __launch_bounds__(256) void wtconv_fused(
    const float* __restrict__ x, const float* __restrict__ bw,
    const float* __restrict__ bs, const float* __restrict__ ww,
    const float* __restrict__ wsc, float* __restrict__ out,
    float* __restrict__ nrm) {
  constexpr int NT = HP / 64;            // tiles per side
  const int tile = blockIdx.x;
  const int c = blockIdx.y, b = blockIdx.z;
  const int oy = (tile / NT) * 64, ox = (tile % NT) * 64;
  const float* xp = x + ((size_t)(b * C_) + c) * HP * HP;

  __shared__ float xt[68][72];           // input tile + 2-halo
  __shared__ float sb[4][34][36];        // subbands + 1-halo
  __shared__ float red[4];

  // uniform (per-block) weights
  float wb[9];
#pragma unroll
  for (int i = 0; i < 9; ++i) wb[i] = bw[c * 9 + i];
  const float sbase = bs[c];
  float wv[4][9]; float sv[4];
#pragma unroll
  for (int f = 0; f < 4; ++f) {
#pragma unroll
    for (int i = 0; i < 9; ++i) wv[f][i] = ww[(c * 4 + f) * 9 + i];
    sv[f] = wsc[c * 4 + f];
  }

  const int t = threadIdx.x;
  // stage input 68x68 (zero outside plane)
  for (int p = t; p < 68 * 68; p += 256) {
    int r = p / 68, cc = p % 68;
    int gy = oy - 2 + r, gx = ox - 2 + cc;
    float v = 0.f;
    if ((unsigned)gy < (unsigned)HP && (unsigned)gx < (unsigned)HP)
      v = xp[gy * HP + gx];
    xt[r][cc] = v;
  }
  __syncthreads();
  // Haar analysis: 34x34 subband positions (tile-local, incl. 1-halo)
  for (int p = t; p < 34 * 34; p += 256) {
    int i = p / 34, j = p % 34;
    float p00 = xt[2 * i][2 * j],     p01 = xt[2 * i][2 * j + 1];
    float p10 = xt[2 * i + 1][2 * j], p11 = xt[2 * i + 1][2 * j + 1];
    sb[0][i][j] = 0.5f * (p00 + p01 + p10 + p11);
    sb[1][i][j] = 0.5f * (p00 + p01 - p10 - p11);
    sb[2][i][j] = 0.5f * (p00 - p01 + p10 - p11);
    sb[3][i][j] = 0.5f * (p00 - p01 - p10 + p11);
  }
  __syncthreads();

  float nacc = 0.f;
  float* op0 = out + ((size_t)(b * C_) + c) * HP * HP;
  // 32x32 interior subband positions; each yields a 2x2 output block
  for (int p = t; p < 32 * 32; p += 256) {
    int i = p >> 5, j = p & 31;
    // dw3x3 on each subband (+ scale); interior (i,j) = tile-local (i+1,j+1)
    float s4[4];
#pragma unroll
    for (int f = 0; f < 4; ++f) {
      float a = 0.f;
#pragma unroll
      for (int dh = 0; dh < 3; ++dh)
#pragma unroll
        for (int dw = 0; dw < 3; ++dw)
          a = fmaf(sb[f][i + dh][j + dw], wv[f][dh * 3 + dw], a);
      s4[f] = a * sv[f];
    }
    // base conv: 4x4 input patch covering the 2x2 block's 3x3 windows
    float pp[4][4];
#pragma unroll
    for (int r = 0; r < 4; ++r)
#pragma unroll
      for (int cc = 0; cc < 4; ++cc)
        pp[r][cc] = xt[2 * i + 1 + r][2 * j + 1 + cc];
    float o4[2][2];
#pragma unroll
    for (int di = 0; di < 2; ++di)
#pragma unroll
      for (int dj = 0; dj < 2; ++dj) {
        float a = 0.f;
#pragma unroll
        for (int dh = 0; dh < 3; ++dh)
#pragma unroll
          for (int dw = 0; dw < 3; ++dw)
            a = fmaf(pp[di + dh][dj + dw], wb[dh * 3 + dw], a);
        a *= sbase;
        float s1 = di ? -s4[1] : s4[1];
        float s2 = dj ? -s4[2] : s4[2];
        float s3 = (di ^ dj) ? -s4[3] : s4[3];
        o4[di][dj] = a + 0.5f * (s4[0] + s1 + s2 + s3);
      }
    float* op = op0 + (size_t)(oy + 2 * i) * HP + ox + 2 * j;
    *(float2*)op        = make_float2(o4[0][0], o4[0][1]);
    *(float2*)(op + HP) = make_float2(o4[1][0], o4[1][1]);
    nacc += o4[0][0] * o4[0][0] + o4[0][1] * o4[0][1] +
            o4[1][0] * o4[1][0] + o4[1][1] * o4[1][1];
  }
  if (nrm != nullptr) {
#pragma unroll
    for (int m = 32; m; m >>= 1) nacc += __shfl_xor(nacc, m, 64);
    int lane = t & 63, wv_ = t >> 6;
    if (lane == 0) red[wv_] = nacc;
    __syncthreads();
    if (t == 0)
      atomicAdd(&nrm[b * C_ + c], red[0] + red[1] + red[2] + red[3]);
  }
}

// ---------------------------------------------------------------------------
// Bilinear 2x upsample 64->128 (align_corners=False == jax.image.resize)
// + fold sum(v^2) per (b,c) row into rnq_sum (each block is within one row)
// ---------------------------------------------------------------------------
__global__ __launch_bounds__(256) void resize2x_norm(const float* __restrict__ in,
                                                     float* __restrict__ out,
                                                     float* __restrict__ rnq_sum) {
  int idx = blockIdx.x * 256 + threadIdx.x;
  int j = idx & (Wb_ - 1); int tmp = idx >> 7;
  int i = tmp & (Hb_ - 1); tmp >>= 7;
  int bc = tmp;
  int ti = i >> 1; bool oi = i & 1;
  int r0 = oi ? ti : ti - 1;  int r1 = oi ? ti + 1 : ti;
  float wr0 = oi ? 0.75f : 0.25f, wr1 = oi ? 0.25f : 0.75f;
  r0 = r0 < 0 ? 0 : r0;  r1 = r1 > Hs_ - 1 ? Hs_ - 1 : r1;
  int tj = j >> 1; bool oj = j & 1;
  int c0 = oj ? tj : tj - 1;  int c1 = oj ? tj + 1 : tj;
  float wc0 = oj ? 0.75f : 0.25f, wc1 = oj ? 0.25f : 0.75f;
  c0 = c0 < 0 ? 0 : c0;  c1 = c1 > Ws_ - 1 ? Ws_ - 1 : c1;
  const float* ip = in + (size_t)bc * Ns_;
  float v = wr0 * (wc0 * ip[r0 * Ws_ + c0] + wc1 * ip[r0 * Ws_ + c1]) +
            wr1 * (wc0 * ip[r1 * Ws_ + c0] + wc1 * ip[r1 * Ws_ + c1]);
  out[idx] = v;
  float nacc = v * v;
#pragma unroll
  for (int m = 32; m; m >>= 1) nacc += __shfl_xor(nacc, m, 64);
  __shared__ float red[4];
  int lane = threadIdx.x & 63, wv = threadIdx.x >> 6;
  if (lane == 0) red[wv] = nacc;
  __syncthreads();
  if (threadIdx.x == 0)
    atomicAdd(&rnq_sum[bc], red[0] + red[1] + red[2] + red[3]);
}

__global__ void zero_buf(float* __restrict__ p, int n) {
  int i = blockIdx.x * blockDim.x + threadIdx.x;
  if (i < n) p[i] = 0.f;
}

// ---------------------------------------------------------------------------
// Gram: gram[b][h][c][d] += sum_{n in slice} q[b][h*32+c][n] * k[b][h*32+d][n]
// ---------------------------------------------------------------------------
__global__ __launch_bounds__(1024) void gram_qk(const float* __restrict__ q,
                                                const float* __restrict__ k,
                                                float* __restrict__ gram) {
  const int b = blockIdx.z, h = blockIdx.y, sl = blockIdx.x;
  constexpr int NS = Nb_ / 32;
  const int n0 = sl * NS;
  const int t = threadIdx.x;
  const int c = t >> 5, d = t & 31;
  const float* qb = q + ((size_t)b * C_ + h * CHD_) * Nb_;
  const float* kb = k + ((size_t)b * C_ + h * CHD_) * Nb_;
  __shared__ float qs[32][66], ks[32][66];
  float acc = 0.f;
  for (int nc = 0; nc < NS; nc += 64) {
    int lr = t >> 5;
    int lc = (t & 31) * 2;
    *(float2*)&qs[lr][lc] = *(const float2*)&qb[(size_t)lr * Nb_ + n0 + nc + lc];
    *(float2*)&ks[lr][lc] = *(const float2*)&kb[(size_t)lr * Nb_ + n0 + nc + lc];
    __syncthreads();
#pragma unroll
    for (int nn = 0; nn < 64; ++nn) acc = fmaf(qs[c][nn], ks[d][nn], acc);
    __syncthreads();
  }
  atomicAdd(&gram[((size_t)(b * HEADS_ + h) * CHD_ + c) * CHD_ + d], acc);
}

// ---------------------------------------------------------------------------
// attn = softmax_d( gram * rsq(c) * rsk(d) * temp_h ), rs = 1/max(sqrt(sum),eps)
// ---------------------------------------------------------------------------
__global__ __launch_bounds__(1024) void attn_softmax(const float* __restrict__ gram,
                                                     const float* __restrict__ rnq_sum,
                                                     const float* __restrict__ rnk_sum,
                                                     const float* __restrict__ temp,
                                                     float* __restrict__ attn) {
  const int h = blockIdx.x, b = blockIdx.y;
  const int t = threadIdx.x;
  const int c = t >> 5, d = t & 31;
  size_t gi = ((size_t)(b * HEADS_ + h) * CHD_ + c) * CHD_ + d;
  float rq = 1.f / fmaxf(sqrtf(rnq_sum[b * C_ + h * CHD_ + c]), 1e-12f);
  float rk = 1.f / fmaxf(sqrtf(rnk_sum[b * C_ + h * CHD_ + d]), 1e-12f);
  float val = gram[gi] * rq * rk * temp[h];
  float m = val;
#pragma unroll
  for (int s = 16; s; s >>= 1) m = fmaxf(m, __shfl_xor(m, s, 64));
  float e = expf(val - m);
  float ssum = e;
#pragma unroll
  for (int s = 16; s; s >>= 1) ssum += __shfl_xor(ssum, s, 64);
  attn[gi] = e / ssum;
}

// ---------------------------------------------------------------------------
// Fused attn@v + proj-wtconv (1x1 kernels => per-2x2-block closed form).
// Block: (tile of 128 2x2-blocks) x (b,h). Thread: one 2x2 block, 16 channels
// (half = tid>>7 selects c range). Writes d_out directly.
// ---------------------------------------------------------------------------
__global__ __launch_bounds__(256) void av_proj(const float* __restrict__ attn,
                                               const float* __restrict__ v,
                                               const float* __restrict__ p_bw,
                                               const float* __restrict__ p_bs,
                                               const float* __restrict__ p_ww,
                                               const float* __restrict__ p_ws,
                                               float* __restrict__ out) {
  const int bh = blockIdx.y;
  const int b = bh >> 3, h = bh & 7;
  const int half = threadIdx.x >> 7;          // 0/1: channels [half*16, half*16+16)
  const int pl = threadIdx.x & 127;
  const int p = blockIdx.x * 128 + pl;        // 2x2-block index in 64x64 grid
  const int bi = p >> 6, bj = p & 63;
  __shared__ float a[32][33];
  for (int i = threadIdx.x; i < 1024; i += 256)
    a[i >> 5][i & 31] = attn[(size_t)bh * 1024 + i];
  __syncthreads();
  const float* vb = v + ((size_t)b * C_ + h * CHD_) * Nb_;
  const int n00 = (2 * bi) * Wb_ + 2 * bj;
  float acc[16][4] = {};
  for (int d = 0; d < 32; ++d) {
    const float* vp = vb + (size_t)d * Nb_ + n00;
    float v00 = vp[0], v01 = vp[1], v10 = vp[Wb_], v11 = vp[Wb_ + 1];
#pragma unroll
    for (int cc = 0; cc < 16; ++cc) {
      float av = a[half * 16 + cc][d];
      acc[cc][0] = fmaf(av, v00, acc[cc][0]);
      acc[cc][1] = fmaf(av, v01, acc[cc][1]);
      acc[cc][2] = fmaf(av, v10, acc[cc][2]);
      acc[cc][3] = fmaf(av, v11, acc[cc][3]);
    }
  }
  float* ob = out + ((size_t)b * C_ + h * CHD_) * Nb_;
#pragma unroll
  for (int cc = 0; cc < 16; ++cc) {
    int lc = half * 16 + cc;            // channel within head
    int gc = h * CHD_ + lc;             // global channel
    float p00 = acc[cc][0], p01 = acc[cc][1], p10 = acc[cc][2], p11 = acc[cc][3];
    float ll = 0.5f * (p00 + p01 + p10 + p11) * (p_ww[gc * 4 + 0] * p_ws[gc * 4 + 0]);
    float hl = 0.5f * (p00 + p01 - p10 - p11) * (p_ww[gc * 4 + 1] * p_ws[gc * 4 + 1]);
    float lh = 0.5f * (p00 - p01 + p10 - p11) * (p_ww[gc * 4 + 2] * p_ws[gc * 4 + 2]);
    float hh = 0.5f * (p00 - p01 - p10 + p11) * (p_ww[gc * 4 + 3] * p_ws[gc * 4 + 3]);
    float bb = p_bw[gc] * p_bs[gc];
    float* op = ob + (size_t)lc * Nb_ + n00;
    *(float2*)op         = make_float2(p00 * bb + 0.5f * (ll + hl + lh + hh),
                                       p01 * bb + 0.5f * (ll + hl - lh - hh));
    *(float2*)(op + Wb_) = make_float2(p10 * bb + 0.5f * (ll - hl + lh - hh),
                                       p11 * bb + 0.5f * (ll - hl - lh + hh));
  }
}

// ---------------------------------------------------------------------------
extern "C" void kernel_launch(void* const* d_in, const int* in_sizes, int n_in,
                              void* d_out, int out_size, void* d_ws, size_t ws_size,
                              hipStream_t stream) {
  const float* x    = (const float*)d_in[0];
  const float* cf   = (const float*)d_in[1];
  const float* Wq   = (const float*)d_in[2];
  const float* Wk   = (const float*)d_in[3];
  const float* Wv   = (const float*)d_in[4];
  const float* temp = (const float*)d_in[5];
  const float* q_bw = (const float*)d_in[6];
  const float* q_bs = (const float*)d_in[7];
  const float* q_ww = (const float*)d_in[8];
  const float* q_ws = (const float*)d_in[9];
  const float* k_bw = (const float*)d_in[10];
  const float* k_bs = (const float*)d_in[11];
  const float* k_ww = (const float*)d_in[12];
  const float* k_ws = (const float*)d_in[13];
  const float* v_bw = (const float*)d_in[14];
  const float* v_bs = (const float*)d_in[15];
  const float* v_ww = (const float*)d_in[16];
  const float* v_ws = (const float*)d_in[17];
  const float* p_bw = (const float*)d_in[18];
  const float* p_bs = (const float*)d_in[19];
  const float* p_ww = (const float*)d_in[20];
  const float* p_ws = (const float*)d_in[21];

  // Workspace (floats); liveness reuse: Bb = k0 -> q_up.
  float* ws   = (float*)d_ws;
  float* A    = ws;                 // q0 [2,256,64,64]      2,097,152
  float* Bb   = A  + 2097152;       // k0 -> q_up            8,388,608
  float* Cb   = Bb + 8388608;       // v0                    8,388,608
  float* Fb   = Cb + 8388608;       // q1 [2,256,64,64]      2,097,152
  float* Gb   = Fb + 2097152;       // k1                    8,388,608
  float* Hb   = Gb + 8388608;       // v1                    8,388,608
  float* rnq  = Hb + 8388608;       // 512   (sumsq, atomic)
  float* rnk  = rnq + 512;          // 512   (sumsq, atomic)
  float* gram = rnk + 512;          // 16384 (atomic)
  float* attn = gram + 16384;       // 16384

  // 0) zero the atomic accumulators (rnq|rnk|gram contiguous = 17408 floats)
  zero_buf<<<(17408 + 255) / 256, 256, 0, stream>>>(rnq, 17408);

  // 1) q/k/v 1x1 channel-mix GEMMs
  gemm_1x1<Ns_><<<dim3(Ns_ / 128, C_ / 64, B_), 256, 0, stream>>>(x,  Wq, A);
  gemm_1x1<Nb_><<<dim3(Nb_ / 128, C_ / 64, B_), 256, 0, stream>>>(cf, Wk, Bb);
  gemm_1x1<Nb_><<<dim3(Nb_ / 128, C_ / 64, B_), 256, 0, stream>>>(cf, Wv, Cb);

  // 2) fused wtconv: q (64x64), k (128x128, +norm fold), v (128x128)
  wtconv_fused<64><<<dim3(1, C_, B_), 256, 0, stream>>>(A, q_bw, q_bs, q_ww, q_ws, Fb, nullptr);
  wtconv_fused<128><<<dim3(4, C_, B_), 256, 0, stream>>>(Bb, k_bw, k_bs, k_ww, k_ws, Gb, rnk);
  wtconv_fused<128><<<dim3(4, C_, B_), 256, 0, stream>>>(Cb, v_bw, v_bs, v_ww, v_ws, Hb, nullptr);

  // 3) upsample q1 -> q_up (into Bb; k0 dead) + rnq fold
  resize2x_norm<<<B_ * C_ * Nb_ / 256, 256, 0, stream>>>(Fb, Bb, rnq);

  // 4) gram + softmax
  gram_qk<<<dim3(32, HEADS_, B_), 1024, 0, stream>>>(Bb, Gb, gram);
  attn_softmax<<<dim3(HEADS_, B_), 1024, 0, stream>>>(gram, rnq, rnk, temp, attn);

  // 5) fused attn@v + proj -> d_out
  av_proj<<<dim3(Nb_ / 4 / 128, B_ * HEADS_), 256, 0, stream>>>(
      attn, Hb, p_bw, p_bs, p_ww, p_ws, (float*)d_out);
}

// Round 5
// 378.212 us; speedup vs baseline: 1.6754x; 1.2839x over previous
//
#include <hip/hip_runtime.h>
#include <math.h>

// WaveletAtt: B=2, CIN=DIM=256, HEADS=8, wt_levels=1 Haar
constexpr int B_ = 2;
constexpr int C_ = 256;
constexpr int Hb_ = 128, Wb_ = 128;      // crossFeat / k / v / output spatial
constexpr int Nb_ = Hb_ * Wb_;           // 16384
constexpr int Hs_ = 64, Ws_ = 64;        // x / q spatial
constexpr int Ns_ = Hs_ * Ws_;           // 4096
constexpr int HEADS_ = 8;
constexpr int CHD_ = C_ / HEADS_;        // 32

// ---------------------------------------------------------------------------
// GEMM: out[b][o][n] = sum_c W[o][c] * in[b][c][n]
// 64(M)x128(N) tile, 256 threads, 4x8 micro-tile, BK=32.
// Thread columns: tx*4 and tx*4+64 (2-way LDS banks = free); all LDS reads b128.
// ---------------------------------------------------------------------------
template<int NTOT>
__global__ __launch_bounds__(256) void gemm_1x1(const float* __restrict__ in,
                                                const float* __restrict__ Wm,
                                                float* __restrict__ out) {
  constexpr int BK = 32;
  __shared__ float Wsh[BK][68];    // [k][o], pad 68 keeps b128 alignment
  __shared__ float Xsh[BK][128];   // [k][n]
  const int b  = blockIdx.z;
  const int o0 = blockIdx.y * 64;
  const int n0 = blockIdx.x * 128;
  const float* inb = in + (size_t)b * C_ * NTOT;
  const int t  = threadIdx.x;
  const int ty = t >> 4, tx = t & 15;   // ty: 4 M-rows; tx: cols tx*4, tx*4+64
  float acc[4][8] = {};
  for (int k0 = 0; k0 < C_; k0 += BK) {
    { // stage W tile (64 o x 32 k): 8 k per thread from one o-row
      int oo = t >> 2, kb = (t & 3) << 3;
      const float* wp = Wm + (size_t)(o0 + oo) * C_ + k0 + kb;
      float4 w0 = *(const float4*)wp;
      float4 w1 = *(const float4*)(wp + 4);
      Wsh[kb + 0][oo] = w0.x; Wsh[kb + 1][oo] = w0.y;
      Wsh[kb + 2][oo] = w0.z; Wsh[kb + 3][oo] = w0.w;
      Wsh[kb + 4][oo] = w1.x; Wsh[kb + 5][oo] = w1.y;
      Wsh[kb + 6][oo] = w1.z; Wsh[kb + 7][oo] = w1.w;
    }
    { // stage X tile (32 k x 128 n)
      int nn = (t & 31) << 2;
      int kr0 = t >> 5;
#pragma unroll
      for (int r = 0; r < 4; ++r) {
        int kr = kr0 + r * 8;
        *(float4*)&Xsh[kr][nn] = *(const float4*)(inb + (size_t)(k0 + kr) * NTOT + n0 + nn);
      }
    }
    __syncthreads();
#pragma unroll
    for (int kk = 0; kk < BK; ++kk) {
      float4 af = *(float4*)&Wsh[kk][ty * 4];
      float4 x0 = *(float4*)&Xsh[kk][tx * 4];
      float4 x1 = *(float4*)&Xsh[kk][tx * 4 + 64];
      float av[4] = {af.x, af.y, af.z, af.w};
      float xv[8] = {x0.x, x0.y, x0.z, x0.w, x1.x, x1.y, x1.z, x1.w};
#pragma unroll
      for (int i = 0; i < 4; ++i)
#pragma unroll
        for (int j = 0; j < 8; ++j)
          acc[i][j] = fmaf(av[i], xv[j], acc[i][j]);
    }
    __syncthreads();
  }
  float* ob = out + (size_t)b * C_ * NTOT;
#pragma unroll
  for (int i = 0; i < 4; ++i) {
    float* op = ob + (size_t)(o0 + ty * 4 + i) * NTOT + n0;
    *(float4*)(op + tx * 4)      = make_float4(acc[i][0], acc[i][1], acc[i][2], acc[i][3]);
    *(float4*)(op + tx * 4 + 64) = make_float4(acc[i][4], acc[i][5], acc[i][6], acc[i][7]);
  }
}

// ---------------------------------------------------------------------------
// Fused WTConv (wt_levels=1 Haar): analysis -> dw3x3*scale -> synthesis +
// base dw3x3*base_s, one 64x64 output tile per block, all staged in LDS.
// Optional sum(out^2) per (b,c) row into nrm (atomic; zeroed beforehand).
// ---------------------------------------------------------------------------
template<int HP>   // plane is HP x HP (64 or 128)
__global__ __launch_bounds__(256) void wtconv_fused(
    const float* __restrict__ x, const float* __restrict__ bw,
    const float* __restrict__ bs, const float* __restrict__ ww,
    const float* __restrict__ wsc, float* __restrict__ out,
    float* __restrict__ nrm) {
  constexpr int NT = HP / 64;
  const int tile = blockIdx.x;
  const int c = blockIdx.y, b = blockIdx.z;
  const int oy = (tile / NT) * 64, ox = (tile % NT) * 64;
  const float* xp = x + ((size_t)(b * C_) + c) * HP * HP;

  __shared__ float xt[68][72];
  __shared__ float sb[4][34][36];
  __shared__ float red[4];

  float wb[9];
#pragma unroll
  for (int i = 0; i < 9; ++i) wb[i] = bw[c * 9 + i];
  const float sbase = bs[c];
  float wv[4][9]; float sv[4];
#pragma unroll
  for (int f = 0; f < 4; ++f) {
#pragma unroll
    for (int i = 0; i < 9; ++i) wv[f][i] = ww[(c * 4 + f) * 9 + i];
    sv[f] = wsc[c * 4 + f];
  }

  const int t = threadIdx.x;
  for (int p = t; p < 68 * 68; p += 256) {
    int r = p / 68, cc = p % 68;
    int gy = oy - 2 + r, gx = ox - 2 + cc;
    float v = 0.f;
    if ((unsigned)gy < (unsigned)HP && (unsigned)gx < (unsigned)HP)
      v = xp[gy * HP + gx];
    xt[r][cc] = v;
  }
  __syncthreads();
  for (int p = t; p < 34 * 34; p += 256) {
    int i = p / 34, j = p % 34;
    float p00 = xt[2 * i][2 * j],     p01 = xt[2 * i][2 * j + 1];
    float p10 = xt[2 * i + 1][2 * j], p11 = xt[2 * i + 1][2 * j + 1];
    sb[0][i][j] = 0.5f * (p00 + p01 + p10 + p11);
    sb[1][i][j] = 0.5f * (p00 + p01 - p10 - p11);
    sb[2][i][j] = 0.5f * (p00 - p01 + p10 - p11);
    sb[3][i][j] = 0.5f * (p00 - p01 - p10 + p11);
  }
  __syncthreads();

  float nacc = 0.f;
  float* op0 = out + ((size_t)(b * C_) + c) * HP * HP;
  for (int p = t; p < 32 * 32; p += 256) {
    int i = p >> 5, j = p & 31;
    float s4[4];
#pragma unroll
    for (int f = 0; f < 4; ++f) {
      float a = 0.f;
#pragma unroll
      for (int dh = 0; dh < 3; ++dh)
#pragma unroll
        for (int dw = 0; dw < 3; ++dw)
          a = fmaf(sb[f][i + dh][j + dw], wv[f][dh * 3 + dw], a);
      s4[f] = a * sv[f];
    }
    float pp[4][4];
#pragma unroll
    for (int r = 0; r < 4; ++r)
#pragma unroll
      for (int cc = 0; cc < 4; ++cc)
        pp[r][cc] = xt[2 * i + 1 + r][2 * j + 1 + cc];
    float o4[2][2];
#pragma unroll
    for (int di = 0; di < 2; ++di)
#pragma unroll
      for (int dj = 0; dj < 2; ++dj) {
        float a = 0.f;
#pragma unroll
        for (int dh = 0; dh < 3; ++dh)
#pragma unroll
          for (int dw = 0; dw < 3; ++dw)
            a = fmaf(pp[di + dh][dj + dw], wb[dh * 3 + dw], a);
        a *= sbase;
        float s1 = di ? -s4[1] : s4[1];
        float s2 = dj ? -s4[2] : s4[2];
        float s3 = (di ^ dj) ? -s4[3] : s4[3];
        o4[di][dj] = a + 0.5f * (s4[0] + s1 + s2 + s3);
      }
    float* op = op0 + (size_t)(oy + 2 * i) * HP + ox + 2 * j;
    *(float2*)op        = make_float2(o4[0][0], o4[0][1]);
    *(float2*)(op + HP) = make_float2(o4[1][0], o4[1][1]);
    nacc += o4[0][0] * o4[0][0] + o4[0][1] * o4[0][1] +
            o4[1][0] * o4[1][0] + o4[1][1] * o4[1][1];
  }
  if (nrm != nullptr) {
#pragma unroll
    for (int m = 32; m; m >>= 1) nacc += __shfl_xor(nacc, m, 64);
    int lane = t & 63, wv_ = t >> 6;
    if (lane == 0) red[wv_] = nacc;
    __syncthreads();
    if (t == 0)
      atomicAdd(&nrm[b * C_ + c], red[0] + red[1] + red[2] + red[3]);
  }
}

// ---------------------------------------------------------------------------
// Bilinear 2x upsample 64->128, one block per (b,c) plane. Input plane in LDS,
// each thread emits 16 float4 (64 outputs). Row-norm direct-stored (no atomic).
// ---------------------------------------------------------------------------
__global__ __launch_bounds__(256) void resize2x_norm(const float* __restrict__ in,
                                                     float* __restrict__ out,
                                                     float* __restrict__ rnq_sum) {
  const int bc = blockIdx.x;
  const int t = threadIdx.x;
  __shared__ float xs[64][65];   // pad 65: stride-2 col reads -> 2-way (free)
  __shared__ float red[4];
  const float* ip = in + (size_t)bc * Ns_;
  for (int p = t; p < 1024; p += 256) {
    float4 v = *(const float4*)&ip[p << 2];
    int r = p >> 4, c0 = (p & 15) << 2;
    xs[r][c0] = v.x; xs[r][c0 + 1] = v.y; xs[r][c0 + 2] = v.z; xs[r][c0 + 3] = v.w;
  }
  __syncthreads();
  float* op = out + (size_t)bc * Nb_;
  float nacc = 0.f;
#pragma unroll
  for (int it = 0; it < 16; ++it) {
    int p = t + it * 256;          // float4 index in 128x128 output
    int i = p >> 5;                // output row
    int jc = p & 31;               // float4 col group
    int ti = i >> 1; bool oi = i & 1;
    int r0 = oi ? ti : (ti > 0 ? ti - 1 : 0);
    int r1 = oi ? (ti < 63 ? ti + 1 : 63) : ti;
    float wr0 = oi ? 0.75f : 0.25f, wr1 = oi ? 0.25f : 0.75f;
    int cb = jc << 1;
    int cm1 = cb > 0 ? cb - 1 : 0;
    int cp2 = cb < 62 ? cb + 2 : 63;
    float a0 = xs[r0][cm1], a1 = xs[r0][cb], a2 = xs[r0][cb + 1], a3 = xs[r0][cp2];
    float b0 = xs[r1][cm1], b1 = xs[r1][cb], b2 = xs[r1][cb + 1], b3 = xs[r1][cp2];
    // horizontal interpolants (cols 4jc .. 4jc+3)
    float ha0 = 0.25f * a0 + 0.75f * a1, hb0 = 0.25f * b0 + 0.75f * b1;
    float ha1 = 0.75f * a1 + 0.25f * a2, hb1 = 0.75f * b1 + 0.25f * b2;
    float ha2 = 0.25f * a1 + 0.75f * a2, hb2 = 0.25f * b1 + 0.75f * b2;
    float ha3 = 0.75f * a2 + 0.25f * a3, hb3 = 0.75f * b2 + 0.25f * b3;
    float4 o = make_float4(wr0 * ha0 + wr1 * hb0, wr0 * ha1 + wr1 * hb1,
                           wr0 * ha2 + wr1 * hb2, wr0 * ha3 + wr1 * hb3);
    *(float4*)&op[p << 2] = o;
    nacc += o.x * o.x + o.y * o.y + o.z * o.z + o.w * o.w;
  }
#pragma unroll
  for (int m = 32; m; m >>= 1) nacc += __shfl_xor(nacc, m, 64);
  int lane = t & 63, wv = t >> 6;
  if (lane == 0) red[wv] = nacc;
  __syncthreads();
  if (t == 0) rnq_sum[bc] = red[0] + red[1] + red[2] + red[3];
}

__global__ void zero_buf(float* __restrict__ p, int n) {
  int i = blockIdx.x * blockDim.x + threadIdx.x;
  if (i < n) p[i] = 0.f;
}

// ---------------------------------------------------------------------------
// Gram: gram[b][h][c][d] += sum_{n in slice} q[..c..][n] * k[..d..][n]
// grid (16, 8, 2), block 1024; 128-wide chunks staged as float4.
// ---------------------------------------------------------------------------
__global__ __launch_bounds__(1024) void gram_qk(const float* __restrict__ q,
                                                const float* __restrict__ k,
                                                float* __restrict__ gram) {
  const int b = blockIdx.z, h = blockIdx.y, sl = blockIdx.x;
  constexpr int NS = Nb_ / 16;   // 1024 n per slice
  const int n0 = sl * NS;
  const int t = threadIdx.x;
  const int c = t >> 5, d = t & 31;
  const float* qb = q + ((size_t)b * C_ + h * CHD_) * Nb_;
  const float* kb = k + ((size_t)b * C_ + h * CHD_) * Nb_;
  __shared__ float qs[32][132], ks[32][132];
  float acc = 0.f;
  for (int nc = 0; nc < NS; nc += 128) {
    int lr = t >> 5, lc4 = (t & 31) << 2;
    *(float4*)&qs[lr][lc4] = *(const float4*)&qb[(size_t)lr * Nb_ + n0 + nc + lc4];
    *(float4*)&ks[lr][lc4] = *(const float4*)&kb[(size_t)lr * Nb_ + n0 + nc + lc4];
    __syncthreads();
#pragma unroll 8
    for (int nn = 0; nn < 128; ++nn) acc = fmaf(qs[c][nn], ks[d][nn], acc);
    __syncthreads();
  }
  atomicAdd(&gram[((size_t)(b * HEADS_ + h) * CHD_ + c) * CHD_ + d], acc);
}

// ---------------------------------------------------------------------------
// attn = softmax_d( gram * rsq(c) * rsk(d) * temp_h ), rs = 1/max(sqrt(sum),eps)
// ---------------------------------------------------------------------------
__global__ __launch_bounds__(1024) void attn_softmax(const float* __restrict__ gram,
                                                     const float* __restrict__ rnq_sum,
                                                     const float* __restrict__ rnk_sum,
                                                     const float* __restrict__ temp,
                                                     float* __restrict__ attn) {
  const int h = blockIdx.x, b = blockIdx.y;
  const int t = threadIdx.x;
  const int c = t >> 5, d = t & 31;
  size_t gi = ((size_t)(b * HEADS_ + h) * CHD_ + c) * CHD_ + d;
  float rq = 1.f / fmaxf(sqrtf(rnq_sum[b * C_ + h * CHD_ + c]), 1e-12f);
  float rk = 1.f / fmaxf(sqrtf(rnk_sum[b * C_ + h * CHD_ + d]), 1e-12f);
  float val = gram[gi] * rq * rk * temp[h];
  float m = val;
#pragma unroll
  for (int s = 16; s; s >>= 1) m = fmaxf(m, __shfl_xor(m, s, 64));
  float e = expf(val - m);
  float ssum = e;
#pragma unroll
  for (int s = 16; s; s >>= 1) ssum += __shfl_xor(ssum, s, 64);
  attn[gi] = e / ssum;
}

// ---------------------------------------------------------------------------
// Fused attn@v + proj-wtconv (1x1 kernels => per-2x2-block closed form).
// attn staged TRANSPOSED (at[d][c], pad 36) so per-d weights are b128 reads.
// ---------------------------------------------------------------------------
__global__ __launch_bounds__(256) void av_proj(const float* __restrict__ attn,
                                               const float* __restrict__ v,
                                               const float* __restrict__ p_bw,
                                               const float* __restrict__ p_bs,
                                               const float* __restrict__ p_ww,
                                               const float* __restrict__ p_ws,
                                               float* __restrict__ out) {
  const int bh = blockIdx.y;
  const int b = bh >> 3, h = bh & 7;
  const int half = threadIdx.x >> 7;          // channels [half*16, half*16+16)
  const int pl = threadIdx.x & 127;
  const int p = blockIdx.x * 128 + pl;        // 2x2-block index in 64x64 grid
  const int bi = p >> 6, bj = p & 63;
  __shared__ float at[32][36];                // [d][c]
  for (int i = threadIdx.x; i < 1024; i += 256)
    at[i & 31][i >> 5] = attn[(size_t)bh * 1024 + i];
  __syncthreads();
  const float* vb = v + ((size_t)b * C_ + h * CHD_) * Nb_;
  const int n00 = (2 * bi) * Wb_ + 2 * bj;
  float acc[16][4] = {};
  for (int d = 0; d < 32; ++d) {
    const float* vp = vb + (size_t)d * Nb_ + n00;
    float v00 = vp[0], v01 = vp[1], v10 = vp[Wb_], v11 = vp[Wb_ + 1];
    float4 a0 = *(float4*)&at[d][half * 16];
    float4 a1 = *(float4*)&at[d][half * 16 + 4];
    float4 a2 = *(float4*)&at[d][half * 16 + 8];
    float4 a3 = *(float4*)&at[d][half * 16 + 12];
    float av[16] = {a0.x, a0.y, a0.z, a0.w, a1.x, a1.y, a1.z, a1.w,
                    a2.x, a2.y, a2.z, a2.w, a3.x, a3.y, a3.z, a3.w};
#pragma unroll
    for (int cc = 0; cc < 16; ++cc) {
      acc[cc][0] = fmaf(av[cc], v00, acc[cc][0]);
      acc[cc][1] = fmaf(av[cc], v01, acc[cc][1]);
      acc[cc][2] = fmaf(av[cc], v10, acc[cc][2]);
      acc[cc][3] = fmaf(av[cc], v11, acc[cc][3]);
    }
  }
  float* ob = out + ((size_t)b * C_ + h * CHD_) * Nb_;
#pragma unroll
  for (int cc = 0; cc < 16; ++cc) {
    int lc = half * 16 + cc;
    int gc = h * CHD_ + lc;
    float p00 = acc[cc][0], p01 = acc[cc][1], p10 = acc[cc][2], p11 = acc[cc][3];
    float ll = 0.5f * (p00 + p01 + p10 + p11) * (p_ww[gc * 4 + 0] * p_ws[gc * 4 + 0]);
    float hl = 0.5f * (p00 + p01 - p10 - p11) * (p_ww[gc * 4 + 1] * p_ws[gc * 4 + 1]);
    float lh = 0.5f * (p00 - p01 + p10 - p11) * (p_ww[gc * 4 + 2] * p_ws[gc * 4 + 2]);
    float hh = 0.5f * (p00 - p01 - p10 + p11) * (p_ww[gc * 4 + 3] * p_ws[gc * 4 + 3]);
    float bb = p_bw[gc] * p_bs[gc];
    float* op = ob + (size_t)lc * Nb_ + n00;
    *(float2*)op         = make_float2(p00 * bb + 0.5f * (ll + hl + lh + hh),
                                       p01 * bb + 0.5f * (ll + hl - lh - hh));
    *(float2*)(op + Wb_) = make_float2(p10 * bb + 0.5f * (ll - hl + lh - hh),
                                       p11 * bb + 0.5f * (ll - hl - lh + hh));
  }
}

// ---------------------------------------------------------------------------
extern "C" void kernel_launch(void* const* d_in, const int* in_sizes, int n_in,
                              void* d_out, int out_size, void* d_ws, size_t ws_size,
                              hipStream_t stream) {
  const float* x    = (const float*)d_in[0];
  const float* cf   = (const float*)d_in[1];
  const float* Wq   = (const float*)d_in[2];
  const float* Wk   = (const float*)d_in[3];
  const float* Wv   = (const float*)d_in[4];
  const float* temp = (const float*)d_in[5];
  const float* q_bw = (const float*)d_in[6];
  const float* q_bs = (const float*)d_in[7];
  const float* q_ww = (const float*)d_in[8];
  const float* q_ws = (const float*)d_in[9];
  const float* k_bw = (const float*)d_in[10];
  const float* k_bs = (const float*)d_in[11];
  const float* k_ww = (const float*)d_in[12];
  const float* k_ws = (const float*)d_in[13];
  const float* v_bw = (const float*)d_in[14];
  const float* v_bs = (const float*)d_in[15];
  const float* v_ww = (const float*)d_in[16];
  const float* v_ws = (const float*)d_in[17];
  const float* p_bw = (const float*)d_in[18];
  const float* p_bs = (const float*)d_in[19];
  const float* p_ww = (const float*)d_in[20];
  const float* p_ws = (const float*)d_in[21];

  // Workspace (floats); liveness reuse: Bb = k0 -> q_up.
  float* ws   = (float*)d_ws;
  float* A    = ws;                 // q0 [2,256,64,64]      2,097,152
  float* Bb   = A  + 2097152;       // k0 -> q_up            8,388,608
  float* Cb   = Bb + 8388608;       // v0                    8,388,608
  float* Fb   = Cb + 8388608;       // q1 [2,256,64,64]      2,097,152
  float* Gb   = Fb + 2097152;       // k1                    8,388,608
  float* Hb   = Gb + 8388608;       // v1                    8,388,608
  float* rnq  = Hb + 8388608;       // 512   (sumsq, direct write)
  float* rnk  = rnq + 512;          // 512   (sumsq, atomic)
  float* gram = rnk + 512;          // 16384 (atomic)
  float* attn = gram + 16384;       // 16384

  // 0) zero the atomic accumulators (rnk|gram contiguous = 16896 floats)
  zero_buf<<<(16896 + 255) / 256, 256, 0, stream>>>(rnk, 16896);

  // 1) q/k/v 1x1 channel-mix GEMMs
  gemm_1x1<Ns_><<<dim3(Ns_ / 128, C_ / 64, B_), 256, 0, stream>>>(x,  Wq, A);
  gemm_1x1<Nb_><<<dim3(Nb_ / 128, C_ / 64, B_), 256, 0, stream>>>(cf, Wk, Bb);
  gemm_1x1<Nb_><<<dim3(Nb_ / 128, C_ / 64, B_), 256, 0, stream>>>(cf, Wv, Cb);

  // 2) fused wtconv: q (64x64), k (128x128, +norm fold), v (128x128)
  wtconv_fused<64><<<dim3(1, C_, B_), 256, 0, stream>>>(A, q_bw, q_bs, q_ww, q_ws, Fb, nullptr);
  wtconv_fused<128><<<dim3(4, C_, B_), 256, 0, stream>>>(Bb, k_bw, k_bs, k_ww, k_ws, Gb, rnk);
  wtconv_fused<128><<<dim3(4, C_, B_), 256, 0, stream>>>(Cb, v_bw, v_bs, v_ww, v_ws, Hb, nullptr);

  // 3) upsample q1 -> q_up (into Bb; k0 dead) + rnq direct
  resize2x_norm<<<B_ * C_, 256, 0, stream>>>(Fb, Bb, rnq);

  // 4) gram + softmax
  gram_qk<<<dim3(16, HEADS_, B_), 1024, 0, stream>>>(Bb, Gb, gram);
  attn_softmax<<<dim3(HEADS_, B_), 1024, 0, stream>>>(gram, rnq, rnk, temp, attn);

  // 5) fused attn@v + proj -> d_out
  av_proj<<<dim3(Nb_ / 4 / 128, B_ * HEADS_), 256, 0, stream>>>(
      attn, Hb, p_bw, p_bs, p_ww, p_ws, (float*)d_out);
}